// Round 4
// baseline (273.172 us; speedup 1.0000x reference)
//
#include <hip/hip_runtime.h>
#include <hip/hip_fp16.h>

#define N_    8
#define CIN   128
#define COUT  128
#define H_    128
#define W_    128
#define HO    126
#define WO    126
#define PIXPER (HO*WO)            // 15876
#define TOTPIX (N_*PIXPER)        // 127008
#define PT    128                 // pixels per block
#define BLKPERIMG 125             // ceil(15876/128): last block has 4 valid px
#define NBLK  (N_*BLKPERIMG)      // 1000; bid&7 = image -> XCD

typedef _Float16 f16x8 __attribute__((ext_vector_type(8)));
typedef _Float16 f16x4 __attribute__((ext_vector_type(4)));
typedef float    f32x4 __attribute__((ext_vector_type(4)));

union U4H {
    uint4   u;
    __half2 h[4];
    f16x8   f;
};

// lgkmcnt(0) only; vmcnt=63, expcnt=7 stay un-drained -> gathers cross barrier
#define LGKM_BAR() do { __builtin_amdgcn_s_waitcnt(0xC07F); __builtin_amdgcn_s_barrier(); } while (0)

// ---------------------------------------------------------------------------
// Kernel: input [N][C][H*W] fp32 -> channels-last fp16 [N][H*W][C]
// ---------------------------------------------------------------------------
__global__ __launch_bounds__(256) void transpose_in_kernel(
    const float* __restrict__ in, _Float16* __restrict__ in_cl)
{
    __shared__ float tile[64][65];
    int bid = blockIdx.x;
    int hwt = bid & 255;          // HW/64 = 256
    int ct  = (bid >> 8) & 1;     // C/64 = 2
    int n   = bid >> 9;           // N = 8
    int r0  = threadIdx.x >> 4;   // 0..15
    int c4  = (threadIdx.x & 15) * 4;
    const float* src = in + ((size_t)(n * CIN + ct * 64) * 16384) + hwt * 64;
#pragma unroll
    for (int k = 0; k < 4; ++k) {
        int row = r0 + k * 16;                      // c within tile
        float4 v = *(const float4*)(src + (size_t)row * 16384 + c4);
        *(float4*)&tile[row][c4] = v;               // [c][hw]
    }
    __syncthreads();
    _Float16* dst = in_cl + ((size_t)(n * 16384 + hwt * 64) * 128) + ct * 64;
#pragma unroll
    for (int k = 0; k < 4; ++k) {
        int hw = r0 + k * 16;
        f16x4 o;
        o[0] = (_Float16)tile[c4 + 0][hw];
        o[1] = (_Float16)tile[c4 + 1][hw];
        o[2] = (_Float16)tile[c4 + 2][hw];
        o[3] = (_Float16)tile[c4 + 3][hw];
        *(f16x4*)(dst + (size_t)hw * 128 + c4) = o;
    }
}

// ---------------------------------------------------------------------------
// Kernel: weight [O][C][3][3] fp32 -> wt [tap][O][C] fp16 (c contiguous)
// ---------------------------------------------------------------------------
__global__ void transpose_w_kernel(const float* __restrict__ w, _Float16* __restrict__ wt) {
    int t = blockIdx.x * 256 + threadIdx.x;   // 16384 threads
    int o = t >> 7, c = t & 127;
    const float* s = w + (size_t)(o * 128 + c) * 9;
#pragma unroll
    for (int tap = 0; tap < 9; ++tap)
        wt[tap * 16384 + o * 128 + c] = (_Float16)s[tap];
}

// ---------------------------------------------------------------------------
// Main kernel. Block = 128 px x 128 o, 4 waves, wave tile 128o x 32px.
// Raw lgkm-only barriers (2/tap): sW WAR + visibility, NO vmcnt drain ->
// gather loads stay outstanding across barriers. Params are wave-private
// (lanes<32 produce, own wave consumes; no barrier). Rate bilinear fused.
// Epilogue: LDS-staged (union with sW), 128B-contiguous float4 stores.
// ---------------------------------------------------------------------------
__global__ __launch_bounds__(256, 4) void adc_main(
    const _Float16* __restrict__ in_cl, const _Float16* __restrict__ wt,
    const float* __restrict__ rates, const float* __restrict__ bias,
    float* __restrict__ out)
{
    __shared__ union LDSU {
        struct { uint4 W[2048]; uint4 Off[4][32]; uint2 Wgt[4][32]; } s; // 35840 B
        float F[64 * 132];                                              // 33792 B
    } u;

    const int t    = threadIdx.x;
    const int lane = t & 63;
    const int wv   = t >> 6;
    const int l15  = lane & 15;
    const int quad = lane >> 4;

    const int n     = blockIdx.x & 7;           // image == XCD slab
    const int pbase = (blockIdx.x >> 3) * PT;   // within-image pixel base
    const unsigned nb = ((unsigned)n << 14);

    // ---- tap-invariant per-pixel identity + fused rate (lanes<32/wave) ----
    int ho = 0, wo = 0;
    float r = 0.0f;
    if (lane < 32) {
        int rem = min(pbase + wv * 32 + lane, PIXPER - 1);
        ho = rem / WO;
        wo = rem - ho * WO;
        const float sc = 32.0f / 126.0f;
        float sy = fminf(fmaxf(((float)ho + 0.5f) * sc - 0.5f, 0.0f), 31.0f);
        float sx = fminf(fmaxf(((float)wo + 0.5f) * sc - 0.5f, 0.0f), 31.0f);
        int y0 = (int)sy, x0 = (int)sx;
        int y1 = min(y0 + 1, 31), x1 = min(x0 + 1, 31);
        float wy = sy - (float)y0, wx = sx - (float)x0;
        r = rates[y0 * 32 + x0] * (1.0f - wy) * (1.0f - wx)
          + rates[y0 * 32 + x1] * (1.0f - wy) * wx
          + rates[y1 * 32 + x0] * wy * (1.0f - wx)
          + rates[y1 * 32 + x1] * wy * wx;
    }

    f32x4 acc[8][2];
    const f32x4 zero = {0.0f, 0.0f, 0.0f, 0.0f};
#pragma unroll
    for (int i = 0; i < 8; ++i) { acc[i][0] = zero; acc[i][1] = zero; }

#pragma unroll
    for (int tap = 0; tap < 9; ++tap) {
        const int kh = tap / 3;           // compile-time after unroll
        const int kw = tap - kh * 3;

        // ---- stage W[tap] (o x c) into swizzled LDS ----
        const uint4* wsrc = (const uint4*)(wt + tap * 16384);
#pragma unroll
        for (int i = 0; i < 8; ++i) {
            int gi = i * 256 + t;
            int o = gi >> 4, g = gi & 15;
            u.s.W[(o << 4) | (g ^ (o & 7))] = wsrc[gi];
        }
        // ---- per-pixel tap params: wave-private, no cross-wave dep ----
        if (lane < 32) {
            float y = (float)ho + (float)kh * r;
            float x = (float)wo + (float)kw * r;
            float y0f = floorf(y), x0f = floorf(x);
            int y0 = (int)y0f, x0 = (int)x0f;
            float wy = y - y0f, wx = x - x0f;
            float vy0 = (y0 <= H_ - 1) ? 1.0f : 0.0f;
            float vy1 = (y0 <= H_ - 2) ? 1.0f : 0.0f;
            float vx0 = (x0 <= W_ - 1) ? 1.0f : 0.0f;
            float vx1 = (x0 <= W_ - 2) ? 1.0f : 0.0f;
            int yc0 = min(y0, H_ - 1), yc1 = min(y0 + 1, H_ - 1);
            int xc0 = min(x0, W_ - 1), xc1 = min(x0 + 1, W_ - 1);
            uint4 offs;
            offs.x = (nb + (unsigned)(yc0 * W_ + xc0)) << 7;
            offs.y = (nb + (unsigned)(yc0 * W_ + xc1)) << 7;
            offs.z = (nb + (unsigned)(yc1 * W_ + xc0)) << 7;
            offs.w = (nb + (unsigned)(yc1 * W_ + xc1)) << 7;
            u.s.Off[wv][lane] = offs;
            float w00 = (1.0f - wy) * (1.0f - wx) * vy0 * vx0;
            float w01 = (1.0f - wy) * wx * vy0 * vx1;
            float w10 = wy * (1.0f - wx) * vy1 * vx0;
            float w11 = wy * wx * vy1 * vx1;
            uint2 pk;
            pk.x = __builtin_bit_cast(unsigned int, __floats2half2_rn(w00, w01));
            pk.y = __builtin_bit_cast(unsigned int, __floats2half2_rn(w10, w11));
            u.s.Wgt[wv][lane] = pk;
        }
        LGKM_BAR();   // sW[tap] visible to all waves; gathers may stay in flight

        // ---- build B-fragments in registers (dead neighbors skipped) ----
        f16x8 bfrag[2][4];
#pragma unroll
        for (int pt = 0; pt < 2; ++pt) {
            int pl = (pt << 4) + l15;               // 0..31 within wave
            uint4 off = u.s.Off[wv][pl];
            __half2 w00v = {}, w01v = {}, w10v = {}, w11v = {};
            if (kh != 0 || kw != 0) {
                uint2 wpk = u.s.Wgt[wv][pl];
                __half2 wab = __builtin_bit_cast(__half2, wpk.x);
                __half2 wcd = __builtin_bit_cast(__half2, wpk.y);
                w00v = __low2half2(wab); w01v = __high2half2(wab);
                w10v = __low2half2(wcd); w11v = __high2half2(wcd);
            }
            int cg = quad << 3;
#pragma unroll
            for (int ks = 0; ks < 4; ++ks) {
                int cb = ks * 32 + cg;
                U4H A, B, C, D, S;
                A.u = *(const uint4*)(in_cl + off.x + cb);
                if (kw != 0) B.u = *(const uint4*)(in_cl + off.y + cb);
                if (kh != 0) C.u = *(const uint4*)(in_cl + off.z + cb);
                if (kh != 0 && kw != 0) D.u = *(const uint4*)(in_cl + off.w + cb);
                if (kh == 0 && kw == 0) {
                    S.u = A.u;                      // wy=wx=0: weight==1 exact
                } else {
#pragma unroll
                    for (int d = 0; d < 4; ++d) {
                        __half2 s = __hmul2(A.h[d], w00v);
                        if (kw != 0)             s = __hfma2(B.h[d], w01v, s);
                        if (kh != 0)             s = __hfma2(C.h[d], w10v, s);
                        if (kh != 0 && kw != 0)  s = __hfma2(D.h[d], w11v, s);
                        S.h[d] = s;
                    }
                }
                bfrag[pt][ks] = S.f;
            }
        }

        // ---- MFMA: D[o][p] += W[o][c] * S[c][p] ----
#pragma unroll
        for (int ks = 0; ks < 4; ++ks) {
#pragma unroll
            for (int mt = 0; mt < 8; ++mt) {
                int o = (mt << 4) | l15;
                int g = (ks << 2) | quad;
                U4H AF;
                AF.u = u.s.W[(o << 4) | (g ^ (o & 7))];
                acc[mt][0] = __builtin_amdgcn_mfma_f32_16x16x32_f16(AF.f, bfrag[0][ks], acc[mt][0], 0, 0, 0);
                acc[mt][1] = __builtin_amdgcn_mfma_f32_16x16x32_f16(AF.f, bfrag[1][ks], acc[mt][1], 0, 0, 0);
            }
        }
        LGKM_BAR();   // all sW reads retired before tap+1 overwrites
    }

    // ---- epilogue: stage o-halves in LDS, store 128B-contiguous float4 ----
    const int r_   = t >> 2;            // 0..63: o row within half
    const int cseg = (t & 3) * 32;      // 0/32/64/96: px segment
#pragma unroll
    for (int h = 0; h < 2; ++h) {
#pragma unroll
        for (int mt4 = 0; mt4 < 4; ++mt4) {
            int mt    = h * 4 + mt4;
            int o_loc = (mt4 << 4) + (quad << 2);   // o - h*64, rows quad*4+i
#pragma unroll
            for (int pt = 0; pt < 2; ++pt) {
                int px = (wv << 5) + (pt << 4) + l15;
                f32x4 a0 = acc[mt][pt];
                u.F[(o_loc + 0) * 132 + px] = a0[0];
                u.F[(o_loc + 1) * 132 + px] = a0[1];
                u.F[(o_loc + 2) * 132 + px] = a0[2];
                u.F[(o_loc + 3) * 132 + px] = a0[3];
            }
        }
        LGKM_BAR();
        int o = h * 64 + r_;
        float b = bias[o];
        float* obase = out + (size_t)n * (COUT * PIXPER) + (size_t)o * PIXPER + pbase + cseg;
#pragma unroll
        for (int j = 0; j < 8; ++j) {
            int px = cseg + j * 4;
            if (pbase + px + 4 <= PIXPER) {
                f32x4 v = *(f32x4*)&u.F[r_ * 132 + px];
                v[0] += b; v[1] += b; v[2] += b; v[3] += b;
                *(f32x4*)(obase + j * 4) = v;
            }
        }
        if (h == 0) LGKM_BAR();   // before overwriting F with second half
    }
}

// ---------------------------------------------------------------------------
extern "C" void kernel_launch(void* const* d_in, const int* in_sizes, int n_in,
                              void* d_out, int out_size, void* d_ws, size_t ws_size,
                              hipStream_t stream) {
    const float* inputs = (const float*)d_in[0];   // [8,128,128,128]
    const float* weight = (const float*)d_in[1];   // [128,128,3,3]
    const float* rates  = (const float*)d_in[2];   // [1,1,32,32]
    const float* bias   = (const float*)d_in[3];   // [128]
    float* out = (float*)d_out;                    // [8,128,126,126]

    char* ws = (char*)d_ws;
    _Float16* in_cl = (_Float16*)ws;                         // 33,554,432 B
    _Float16* wtp   = (_Float16*)(ws + 33554432);            //    294,912 B

    transpose_w_kernel<<<64, 256, 0, stream>>>(weight, wtp);
    transpose_in_kernel<<<4096, 256, 0, stream>>>(inputs, in_cl);
    adc_main<<<NBLK, 256, 0, stream>>>(in_cl, wtp, rates, bias, out);
}

// Round 5
// 189.607 us; speedup vs baseline: 1.4407x; 1.4407x over previous
//
#include <hip/hip_runtime.h>
#include <hip/hip_fp16.h>

#define N_    8
#define CIN   128
#define COUT  128
#define H_    128
#define W_    128
#define HO    126
#define WO    126
#define PIXPER (HO*WO)            // 15876
#define TOTPIX (N_*PIXPER)        // 127008
#define PT    128                 // pixels per block
#define BLKPERIMG 125             // ceil(15876/128): last block has 4 valid px
#define NBLK  (N_*BLKPERIMG)      // 1000; bid&7 = image
#define SSTR  136                 // fp16 stride of sS px-row (272 B, +16B pad)

typedef _Float16 f16x8 __attribute__((ext_vector_type(8)));
typedef _Float16 f16x4 __attribute__((ext_vector_type(4)));
typedef float    f32x4 __attribute__((ext_vector_type(4)));

union U4H {
    uint4   u;
    __half2 h[4];
    f16x8   f;
};

// ---------------------------------------------------------------------------
// Kernel: input [N][C][H*W] fp32 -> channels-last fp16 [N][H*W][C]
// ---------------------------------------------------------------------------
__global__ __launch_bounds__(256) void transpose_in_kernel(
    const float* __restrict__ in, _Float16* __restrict__ in_cl)
{
    __shared__ float tile[64][65];
    int bid = blockIdx.x;
    int hwt = bid & 255;          // HW/64 = 256
    int ct  = (bid >> 8) & 1;     // C/64 = 2
    int n   = bid >> 9;           // N = 8
    int r0  = threadIdx.x >> 4;   // 0..15
    int c4  = (threadIdx.x & 15) * 4;
    const float* src = in + ((size_t)(n * CIN + ct * 64) * 16384) + hwt * 64;
#pragma unroll
    for (int k = 0; k < 4; ++k) {
        int row = r0 + k * 16;                      // c within tile
        float4 v = *(const float4*)(src + (size_t)row * 16384 + c4);
        *(float4*)&tile[row][c4] = v;               // [c][hw]
    }
    __syncthreads();
    _Float16* dst = in_cl + ((size_t)(n * 16384 + hwt * 64) * 128) + ct * 64;
#pragma unroll
    for (int k = 0; k < 4; ++k) {
        int hw = r0 + k * 16;
        f16x4 o;
        o[0] = (_Float16)tile[c4 + 0][hw];
        o[1] = (_Float16)tile[c4 + 1][hw];
        o[2] = (_Float16)tile[c4 + 2][hw];
        o[3] = (_Float16)tile[c4 + 3][hw];
        *(f16x4*)(dst + (size_t)hw * 128 + c4) = o;
    }
}

// ---------------------------------------------------------------------------
// Kernel: weight [O][C][3][3] fp32 -> wt [tap][O][C] fp16 (c contiguous)
// ---------------------------------------------------------------------------
__global__ void transpose_w_kernel(const float* __restrict__ w, _Float16* __restrict__ wt) {
    int t = blockIdx.x * 256 + threadIdx.x;   // 16384 threads
    int o = t >> 7, c = t & 127;
    const float* s = w + (size_t)(o * 128 + c) * 9;
#pragma unroll
    for (int tap = 0; tap < 9; ++tap)
        wt[tap * 16384 + o * 128 + c] = (_Float16)s[tap];
}

// ---------------------------------------------------------------------------
// Main kernel. Block = 128 px x 128 o, 4 waves.
// Per tap, two phases:
//   A) coalesced gather: 16-lane groups load full 256B channel-rows of each
//      neighbor (2 segments/instr vs 16 before), lerp with per-px broadcast
//      weights, write sampled tile sS[px][c] fp16 (+16B/row pad).
//   B) GEMM: A-frags from sW (swizzled LDS), B-frags from sS, 64 MFMA/wave.
// Tap params precomputed once: (y0,wy) per kh, (x0,wx) per kw — 6 KB LDS.
// LDS 73.7 KB -> 2 blocks/CU.
// ---------------------------------------------------------------------------
__global__ __launch_bounds__(256, 2) void adc_main(
    const _Float16* __restrict__ in_cl, const _Float16* __restrict__ wt,
    const float* __restrict__ rates, const float* __restrict__ bias,
    float* __restrict__ out)
{
    __shared__ uint4    sW[2048];                       // 32768 B
    __shared__ __align__(16) _Float16 sS[PT * SSTR];    // 34816 B
    __shared__ int      sPYi[3][PT];
    __shared__ float    sPYf[3][PT];
    __shared__ int      sPXi[3][PT];
    __shared__ float    sPXf[3][PT];                    // 6144 B

    const int t    = threadIdx.x;
    const int lane = t & 63;
    const int wv   = t >> 6;
    const int l15  = lane & 15;
    const int quad = lane >> 4;

    const int n     = blockIdx.x & 7;
    const int pbase = (blockIdx.x >> 3) * PT;

    // ---- once-per-block param precompute (fused rate bilinear) ----
    if (t < PT) {
        int rem = min(pbase + t, PIXPER - 1);
        int ho = rem / WO, wo = rem - ho * WO;
        const float sc = 32.0f / 126.0f;
        float sy = fminf(fmaxf(((float)ho + 0.5f) * sc - 0.5f, 0.0f), 31.0f);
        float sx = fminf(fmaxf(((float)wo + 0.5f) * sc - 0.5f, 0.0f), 31.0f);
        int y0 = (int)sy, x0 = (int)sx;
        int y1 = min(y0 + 1, 31), x1 = min(x0 + 1, 31);
        float wy = sy - (float)y0, wx = sx - (float)x0;
        float r = rates[y0 * 32 + x0] * (1.0f - wy) * (1.0f - wx)
                + rates[y0 * 32 + x1] * (1.0f - wy) * wx
                + rates[y1 * 32 + x0] * wy * (1.0f - wx)
                + rates[y1 * 32 + x1] * wy * wx;
#pragma unroll
        for (int k = 0; k < 3; ++k) {
            float fy  = (float)ho + (float)k * r;   // exact int when k==0
            float fy0 = floorf(fy);
            sPYi[k][t] = (int)fy0;
            sPYf[k][t] = fy - fy0;
            float fx  = (float)wo + (float)k * r;
            float fx0 = floorf(fx);
            sPXi[k][t] = (int)fx0;
            sPXf[k][t] = fx - fx0;
        }
    }

    f32x4 acc[8][2];
    const f32x4 zero = {0.0f, 0.0f, 0.0f, 0.0f};
#pragma unroll
    for (int i = 0; i < 8; ++i) { acc[i][0] = zero; acc[i][1] = zero; }

    __syncthreads();

    const int grp = t >> 4;        // 16 row-groups
    const int gl  = t & 15;        // lane in group: channel chunk gl*8..gl*8+8
    const unsigned nbase = (unsigned)n << 14;

#pragma unroll
    for (int tap = 0; tap < 9; ++tap) {
        const int kh = tap / 3;            // compile-time after unroll
        const int kw = tap - kh * 3;

        // ---- phase A: stage W[tap] + build sampled tile sS ----
        const uint4* wsrc = (const uint4*)(wt + tap * 16384);
#pragma unroll
        for (int i = 0; i < 8; ++i) {
            int gi = i * 256 + t;
            int o = gi >> 4, g = gi & 15;
            sW[(o << 4) | (g ^ (o & 7))] = wsrc[gi];
        }

#pragma unroll
        for (int j = 0; j < 8; ++j) {
            int px = grp * 8 + j;
            int   y0 = sPYi[kh][px];  float wy = sPYf[kh][px];   // LDS broadcast
            int   x0 = sPXi[kw][px];  float wx = sPXf[kw][px];
            int yc0 = min(y0, H_ - 1), yc1 = min(y0 + 1, H_ - 1);
            int xc0 = min(x0, W_ - 1), xc1 = min(x0 + 1, W_ - 1);
            unsigned lo = (unsigned)(gl * 8);
            U4H A, B, C, D, S;
            A.u = *(const uint4*)(in_cl + (((nbase + (unsigned)(yc0 * W_ + xc0)) << 7) + lo));
            if (kw != 0) B.u = *(const uint4*)(in_cl + (((nbase + (unsigned)(yc0 * W_ + xc1)) << 7) + lo));
            if (kh != 0) C.u = *(const uint4*)(in_cl + (((nbase + (unsigned)(yc1 * W_ + xc0)) << 7) + lo));
            if (kh != 0 && kw != 0)
                         D.u = *(const uint4*)(in_cl + (((nbase + (unsigned)(yc1 * W_ + xc1)) << 7) + lo));
            if (kh == 0 && kw == 0) {
                S.u = A.u;                       // wy=wx=0 exactly: weight==1
            } else {
                float vy0 = (y0 <= H_ - 1) ? 1.0f : 0.0f;
                float vy1 = (y0 <= H_ - 2) ? 1.0f : 0.0f;
                float vx0 = (x0 <= W_ - 1) ? 1.0f : 0.0f;
                float vx1 = (x0 <= W_ - 2) ? 1.0f : 0.0f;
                __half2 w00v = __float2half2_rn((1.0f - wy) * (1.0f - wx) * vy0 * vx0);
                __half2 w01v = __float2half2_rn((1.0f - wy) * wx * vy0 * vx1);
                __half2 w10v = __float2half2_rn(wy * (1.0f - wx) * vy1 * vx0);
                __half2 w11v = __float2half2_rn(wy * wx * vy1 * vx1);
#pragma unroll
                for (int d = 0; d < 4; ++d) {
                    __half2 s = __hmul2(A.h[d], w00v);
                    if (kw != 0)            s = __hfma2(B.h[d], w01v, s);
                    if (kh != 0)            s = __hfma2(C.h[d], w10v, s);
                    if (kh != 0 && kw != 0) s = __hfma2(D.h[d], w11v, s);
                    S.h[d] = s;
                }
            }
            *(f16x8*)&sS[px * SSTR + gl * 8] = S.f;
        }
        __syncthreads();

        // ---- phase B: MFMA, A from sW, B from sS ----
#pragma unroll
        for (int ks = 0; ks < 4; ++ks) {
            f16x8 b0 = *(const f16x8*)&sS[(wv * 32 +      l15) * SSTR + ks * 32 + quad * 8];
            f16x8 b1 = *(const f16x8*)&sS[(wv * 32 + 16 + l15) * SSTR + ks * 32 + quad * 8];
#pragma unroll
            for (int mt = 0; mt < 8; ++mt) {
                int o = (mt << 4) | l15;
                int g = (ks << 2) | quad;
                U4H AF;
                AF.u = sW[(o << 4) | (g ^ (o & 7))];
                acc[mt][0] = __builtin_amdgcn_mfma_f32_16x16x32_f16(AF.f, b0, acc[mt][0], 0, 0, 0);
                acc[mt][1] = __builtin_amdgcn_mfma_f32_16x16x32_f16(AF.f, b1, acc[mt][1], 0, 0, 0);
            }
        }
        __syncthreads();
    }

    // ---- epilogue: R3-proven direct strided stores ----
#pragma unroll
    for (int pt = 0; pt < 2; ++pt) {
        int p    = (wv << 5) + (pt << 4) + l15;
        int prel = pbase + p;
        int rem2 = min(prel, PIXPER - 1);
        float* obase = out + (size_t)n * (COUT * PIXPER) + rem2;
        if (prel < PIXPER) {
#pragma unroll
            for (int mt = 0; mt < 8; ++mt) {
                int o0 = (mt << 4) + (quad << 2);
                float4 bs = *(const float4*)(bias + o0);
                f32x4 a0 = acc[mt][pt];
                obase[(size_t)(o0 + 0) * PIXPER] = a0[0] + bs.x;
                obase[(size_t)(o0 + 1) * PIXPER] = a0[1] + bs.y;
                obase[(size_t)(o0 + 2) * PIXPER] = a0[2] + bs.z;
                obase[(size_t)(o0 + 3) * PIXPER] = a0[3] + bs.w;
            }
        }
    }
}

// ---------------------------------------------------------------------------
extern "C" void kernel_launch(void* const* d_in, const int* in_sizes, int n_in,
                              void* d_out, int out_size, void* d_ws, size_t ws_size,
                              hipStream_t stream) {
    const float* inputs = (const float*)d_in[0];   // [8,128,128,128]
    const float* weight = (const float*)d_in[1];   // [128,128,3,3]
    const float* rates  = (const float*)d_in[2];   // [1,1,32,32]
    const float* bias   = (const float*)d_in[3];   // [128]
    float* out = (float*)d_out;                    // [8,128,126,126]

    char* ws = (char*)d_ws;
    _Float16* in_cl = (_Float16*)ws;                         // 33,554,432 B
    _Float16* wtp   = (_Float16*)(ws + 33554432);            //    294,912 B

    transpose_w_kernel<<<64, 256, 0, stream>>>(weight, wtp);
    transpose_in_kernel<<<4096, 256, 0, stream>>>(inputs, in_cl);
    adc_main<<<NBLK, 256, 0, stream>>>(in_cl, wtp, rates, bias, out);
}